// Round 1
// baseline (1772.621 us; speedup 1.0000x reference)
//
#include <hip/hip_runtime.h>

#define NN 100000
#define NE 600000
#define DIN 128
#define DOUT 64

// ---------------- GEMM1: h0 = x @ W1  (no bias yet) ----------------
// 128 threads = one output column each; 16 rows per block staged in LDS.
__global__ __launch_bounds__(128) void gemm1_kernel(const float* __restrict__ x,
                                                    const float* __restrict__ W,
                                                    float* __restrict__ h0) {
  __shared__ float xs[16][DIN];
  const int row0 = blockIdx.x * 16;
  const int tid = threadIdx.x;
  for (int i = tid; i < 16 * DIN; i += 128) {
    int r = i >> 7, k = i & (DIN - 1);
    int gr = row0 + r;
    xs[r][k] = (gr < NN) ? x[(long)gr * DIN + k] : 0.f;
  }
  __syncthreads();
  const int j = tid;
  float acc[16];
#pragma unroll
  for (int r = 0; r < 16; ++r) acc[r] = 0.f;
  for (int k = 0; k < DIN; ++k) {
    float wj = W[k * DIN + j];          // coalesced across the wave
#pragma unroll
    for (int r = 0; r < 16; ++r) acc[r] += xs[r][k] * wj;  // LDS broadcast
  }
#pragma unroll
  for (int r = 0; r < 16; ++r) {
    int gr = row0 + r;
    if (gr < NN) h0[(long)gr * DIN + j] = acc[r];
  }
}

// ---------------- GEMM2: h2 = relu(h1 + b1) @ W2 ----------------
// 64 threads = one output column each; relu+bias fused into LDS staging.
__global__ __launch_bounds__(64) void gemm2_kernel(const float* __restrict__ h1,
                                                   const float* __restrict__ b1,
                                                   const float* __restrict__ W2,
                                                   float* __restrict__ h2) {
  __shared__ float xs[16][DIN];
  const int row0 = blockIdx.x * 16;
  const int tid = threadIdx.x;
  for (int i = tid; i < 16 * DIN; i += 64) {
    int r = i >> 7, k = i & (DIN - 1);
    int gr = row0 + r;
    float v = (gr < NN) ? (h1[(long)gr * DIN + k] + b1[k]) : 0.f;
    xs[r][k] = v > 0.f ? v : 0.f;
  }
  __syncthreads();
  const int j = tid;
  float acc[16];
#pragma unroll
  for (int r = 0; r < 16; ++r) acc[r] = 0.f;
  for (int k = 0; k < DIN; ++k) {
    float wj = W2[k * DOUT + j];
#pragma unroll
    for (int r = 0; r < 16; ++r) acc[r] += xs[r][k] * wj;
  }
#pragma unroll
  for (int r = 0; r < 16; ++r) {
    int gr = row0 + r;
    if (gr < NN) h2[(long)gr * DOUT + j] = acc[r];
  }
}

// ---------------- SpMM: out[dst] += w_e * h[src], D dims, LPE lanes/edge ----
template <int D, int LPE>
__global__ __launch_bounds__(256) void spmm_kernel(const int* __restrict__ ei,
                                                   const float* __restrict__ ew,
                                                   const float* __restrict__ h,
                                                   float* __restrict__ out) {
  long t = (long)blockIdx.x * blockDim.x + threadIdx.x;
  long e = t / LPE;
  int l = (int)(t % LPE);
  if (e >= NE) return;
  int src = ei[e];
  int dst = ei[NE + e];
  if ((unsigned)src >= NN || (unsigned)dst >= NN) return;  // guard vs dtype surprise
  float we = ew[e];
  const float4 v = ((const float4*)(h + (long)src * D))[l];
  float* o = out + (long)dst * D + l * 4;
  atomicAdd(o + 0, v.x * we);
  atomicAdd(o + 1, v.y * we);
  atomicAdd(o + 2, v.z * we);
  atomicAdd(o + 3, v.w * we);
}

// ---------------- out[n][j] = b2[j] (scatter target pre-seeded w/ bias) -----
__global__ __launch_bounds__(256) void fill_bias_kernel(float* __restrict__ out,
                                                        const float* __restrict__ b2) {
  long t = (long)blockIdx.x * blockDim.x + threadIdx.x;
  if (t < (long)NN * DOUT) out[t] = b2[t & (DOUT - 1)];
}

extern "C" void kernel_launch(void* const* d_in, const int* in_sizes, int n_in,
                              void* d_out, int out_size, void* d_ws, size_t ws_size,
                              hipStream_t stream) {
  const float* x  = (const float*)d_in[0];
  const int*   ei = (const int*)d_in[1];   // edge_index, [2, E] row-major, int32
  const float* ew = (const float*)d_in[2];
  const float* W1 = (const float*)d_in[3];
  const float* b1 = (const float*)d_in[4];
  const float* W2 = (const float*)d_in[5];
  const float* b2 = (const float*)d_in[6];
  float* out = (float*)d_out;

  float* h0   = (float*)d_ws;                 // [NN, DIN] -> later reused as h2 [NN, DOUT]
  float* acc1 = h0 + (size_t)NN * DIN;        // [NN, DIN] layer-1 segment-sum accumulator

  // zero the layer-1 accumulator (ws is re-poisoned to 0xAA each call)
  hipMemsetAsync(acc1, 0, (size_t)NN * DIN * sizeof(float), stream);
  // seed output with bias so the scatter lands on it
  fill_bias_kernel<<<((long)NN * DOUT + 255) / 256, 256, 0, stream>>>(out, b2);

  // layer 1
  gemm1_kernel<<<(NN + 15) / 16, 128, 0, stream>>>(x, W1, h0);
  spmm_kernel<DIN, 32><<<(int)(((long)NE * 32 + 255) / 256), 256, 0, stream>>>(ei, ew, h0, acc1);

  // layer 2 (h2 overwrites the h0 region; acc1 no longer needed after gemm2)
  gemm2_kernel<<<(NN + 15) / 16, 64, 0, stream>>>(acc1, b1, W2, h0);
  spmm_kernel<DOUT, 16><<<(int)(((long)NE * 16 + 255) / 256), 256, 0, stream>>>(ei, ew, h0, out);
}

// Round 2
// 580.378 us; speedup vs baseline: 3.0542x; 3.0542x over previous
//
#include <hip/hip_runtime.h>

#define NN 100000
#define NE 600000
#define DIN 128
#define DOUT 64

// ---------------- CSR build ----------------
__global__ __launch_bounds__(256) void hist_kernel(const int* __restrict__ ei,
                                                   int* __restrict__ cnt) {
  int e = blockIdx.x * 256 + threadIdx.x;
  if (e < NE) atomicAdd(&cnt[ei[NE + e]], 1);
}

// single-block exclusive scan over NN bins -> row_ptr (and a working copy `next`)
__global__ __launch_bounds__(1024) void scan_kernel(const int* __restrict__ cnt,
                                                    int* __restrict__ row_ptr,
                                                    int* __restrict__ next) {
  __shared__ int s[1024];
  const int t = threadIdx.x;
  const int CH = (NN + 1023) / 1024;  // 98
  int lo = t * CH, hi = min(lo + CH, NN);
  int sum = 0;
  for (int i = lo; i < hi; ++i) sum += cnt[i];
  s[t] = sum;
  __syncthreads();
  // Hillis-Steele inclusive scan
  for (int off = 1; off < 1024; off <<= 1) {
    int v = (t >= off) ? s[t - off] : 0;
    __syncthreads();
    s[t] += v;
    __syncthreads();
  }
  int pos = (t > 0) ? s[t - 1] : 0;  // exclusive offset
  for (int i = lo; i < hi; ++i) {
    row_ptr[i] = pos;
    next[i] = pos;
    pos += cnt[i];
  }
  if (t == 1023) row_ptr[NN] = NE;
}

__global__ __launch_bounds__(256) void scatter_kernel(const int* __restrict__ ei,
                                                      const float* __restrict__ ew,
                                                      int* __restrict__ next,
                                                      int* __restrict__ col,
                                                      float* __restrict__ wv) {
  int e = blockIdx.x * 256 + threadIdx.x;
  if (e >= NE) return;
  int src = ei[e];
  int dst = ei[NE + e];
  int pos = atomicAdd(&next[dst], 1);
  col[pos] = src;
  wv[pos] = ew[e];
}

// ---------------- GEMM1: h0 = x @ W1, BM=32, thread = 4 rows x 4 cols -------
__global__ __launch_bounds__(256) void gemm1_kernel(const float* __restrict__ x,
                                                    const float* __restrict__ W,
                                                    float* __restrict__ h0) {
  __shared__ float xs[32][DIN];
  const int t = threadIdx.x;
  const int row0 = blockIdx.x * 32;
  // stage 32x128 tile: 1024 float4, 4 per thread (coalesced)
#pragma unroll
  for (int i = 0; i < 4; ++i) {
    int f = t + i * 256;
    int r = f >> 5, c4 = f & 31;
    *(float4*)&xs[r][c4 * 4] = *(const float4*)&x[(size_t)(row0 + r) * DIN + c4 * 4];
  }
  __syncthreads();
  const int j0 = (t & 31) * 4;
  const int r0 = (t >> 5) * 4;
  float4 acc[4];
#pragma unroll
  for (int i = 0; i < 4; ++i) acc[i] = make_float4(0.f, 0.f, 0.f, 0.f);
  for (int k0 = 0; k0 < DIN; k0 += 4) {
    float4 w[4];
#pragma unroll
    for (int kk = 0; kk < 4; ++kk) w[kk] = *(const float4*)&W[(k0 + kk) * DIN + j0];
#pragma unroll
    for (int i = 0; i < 4; ++i) {
      float4 xr = *(const float4*)&xs[r0 + i][k0];
      acc[i].x += xr.x * w[0].x + xr.y * w[1].x + xr.z * w[2].x + xr.w * w[3].x;
      acc[i].y += xr.x * w[0].y + xr.y * w[1].y + xr.z * w[2].y + xr.w * w[3].y;
      acc[i].z += xr.x * w[0].z + xr.y * w[1].z + xr.z * w[2].z + xr.w * w[3].z;
      acc[i].w += xr.x * w[0].w + xr.y * w[1].w + xr.z * w[2].w + xr.w * w[3].w;
    }
  }
#pragma unroll
  for (int i = 0; i < 4; ++i)
    *(float4*)&h0[(size_t)(row0 + r0 + i) * DIN + j0] = acc[i];
}

// ---------------- GEMM2: h2 = relu(h1 + b1) @ W2, BM=64 ---------------------
__global__ __launch_bounds__(256) void gemm2_kernel(const float* __restrict__ h1,
                                                    const float* __restrict__ b1,
                                                    const float* __restrict__ W2,
                                                    float* __restrict__ h2) {
  __shared__ float xs[64][DIN];
  const int t = threadIdx.x;
  const int row0 = blockIdx.x * 64;
  // stage 64x128 tile with fused bias+relu: 2048 float4, 8 per thread
#pragma unroll
  for (int i = 0; i < 8; ++i) {
    int f = t + i * 256;
    int r = f >> 5, c4 = f & 31;
    int gr = row0 + r;
    float4 v;
    if (gr < NN) {
      v = *(const float4*)&h1[(size_t)gr * DIN + c4 * 4];
      float4 b = *(const float4*)&b1[c4 * 4];
      v.x = fmaxf(v.x + b.x, 0.f);
      v.y = fmaxf(v.y + b.y, 0.f);
      v.z = fmaxf(v.z + b.z, 0.f);
      v.w = fmaxf(v.w + b.w, 0.f);
    } else {
      v = make_float4(0.f, 0.f, 0.f, 0.f);
    }
    *(float4*)&xs[r][c4 * 4] = v;
  }
  __syncthreads();
  const int j0 = (t & 15) * 4;
  const int r0 = (t >> 4) * 4;
  float4 acc[4];
#pragma unroll
  for (int i = 0; i < 4; ++i) acc[i] = make_float4(0.f, 0.f, 0.f, 0.f);
  for (int k0 = 0; k0 < DIN; k0 += 4) {
    float4 w[4];
#pragma unroll
    for (int kk = 0; kk < 4; ++kk) w[kk] = *(const float4*)&W2[(k0 + kk) * DOUT + j0];
#pragma unroll
    for (int i = 0; i < 4; ++i) {
      float4 xr = *(const float4*)&xs[r0 + i][k0];
      acc[i].x += xr.x * w[0].x + xr.y * w[1].x + xr.z * w[2].x + xr.w * w[3].x;
      acc[i].y += xr.x * w[0].y + xr.y * w[1].y + xr.z * w[2].y + xr.w * w[3].y;
      acc[i].z += xr.x * w[0].z + xr.y * w[1].z + xr.z * w[2].z + xr.w * w[3].z;
      acc[i].w += xr.x * w[0].w + xr.y * w[1].w + xr.z * w[2].w + xr.w * w[3].w;
    }
  }
#pragma unroll
  for (int i = 0; i < 4; ++i) {
    int gr = row0 + r0 + i;
    if (gr < NN) *(float4*)&h2[(size_t)gr * DOUT + j0] = acc[i];
  }
}

// ---------------- gather SpMM: out[r] = sum_{e in row r} w_e * h[col[e]] ----
template <int D, int LPE, bool BIAS>
__global__ __launch_bounds__(256) void spmm_gather_kernel(const int* __restrict__ rp,
                                                          const int* __restrict__ col,
                                                          const float* __restrict__ wv,
                                                          const float* __restrict__ h,
                                                          const float* __restrict__ bias,
                                                          float* __restrict__ out) {
  const int row = blockIdx.x * (256 / LPE) + threadIdx.x / LPE;
  const int lane = threadIdx.x % LPE;
  if (row >= NN) return;
  const int b = rp[row], e = rp[row + 1];
  float4 acc = make_float4(0.f, 0.f, 0.f, 0.f);
  for (int i = b; i < e; ++i) {
    int s = col[i];
    float w = wv[i];
    float4 v = *(const float4*)&h[(size_t)s * D + lane * 4];
    acc.x += w * v.x;
    acc.y += w * v.y;
    acc.z += w * v.z;
    acc.w += w * v.w;
  }
  if (BIAS) {
    float4 bv = ((const float4*)bias)[lane];
    acc.x += bv.x; acc.y += bv.y; acc.z += bv.z; acc.w += bv.w;
  }
  *(float4*)&out[(size_t)row * D + lane * 4] = acc;
}

extern "C" void kernel_launch(void* const* d_in, const int* in_sizes, int n_in,
                              void* d_out, int out_size, void* d_ws, size_t ws_size,
                              hipStream_t stream) {
  const float* x  = (const float*)d_in[0];
  const int*   ei = (const int*)d_in[1];   // [2, E] row-major int32
  const float* ew = (const float*)d_in[2];
  const float* W1 = (const float*)d_in[3];
  const float* b1 = (const float*)d_in[4];
  const float* W2 = (const float*)d_in[5];
  const float* b2 = (const float*)d_in[6];
  float* out = (float*)d_out;

  // workspace layout
  char* p = (char*)d_ws;
  int*   cnt     = (int*)p;                 p += sizeof(int) * NN;
  int*   row_ptr = (int*)p;                 p += sizeof(int) * (NN + 4);
  int*   next    = (int*)p;                 p += sizeof(int) * NN;
  int*   col     = (int*)p;                 p += sizeof(int) * NE;
  float* wv      = (float*)p;               p += sizeof(float) * NE;
  float* h0      = (float*)p;               p += sizeof(float) * (size_t)NN * DIN;
  float* acc1    = (float*)p;               // [NN, DIN]
  float* h2      = h0;                      // reuse h0 region after spmm1

  // CSR build (shared by both layers)
  hipMemsetAsync(cnt, 0, sizeof(int) * NN, stream);
  hist_kernel<<<(NE + 255) / 256, 256, 0, stream>>>(ei, cnt);
  scan_kernel<<<1, 1024, 0, stream>>>(cnt, row_ptr, next);
  scatter_kernel<<<(NE + 255) / 256, 256, 0, stream>>>(ei, ew, next, col, wv);

  // layer 1
  gemm1_kernel<<<NN / 32, 256, 0, stream>>>(x, W1, h0);
  spmm_gather_kernel<DIN, 32, false>
      <<<(NN * 32 + 255) / 256, 256, 0, stream>>>(row_ptr, col, wv, h0, nullptr, acc1);

  // layer 2
  gemm2_kernel<<<(NN + 63) / 64, 256, 0, stream>>>(acc1, b1, W2, h2);
  spmm_gather_kernel<DOUT, 16, true>
      <<<(NN * 16 + 255) / 256, 256, 0, stream>>>(row_ptr, col, wv, h2, b2, out);
}

// Round 3
// 364.112 us; speedup vs baseline: 4.8683x; 1.5940x over previous
//
#include <hip/hip_runtime.h>

#define NN 100000
#define NE 600000
#define DIN 128
#define DOUT 64
#define SCAN_B 256
#define NBLK ((NN + SCAN_B - 1) / SCAN_B)  // 391

// ---------------- CSR build ----------------
__global__ __launch_bounds__(256) void hist_kernel(const int* __restrict__ ei,
                                                   int* __restrict__ cnt) {
  int e = blockIdx.x * 256 + threadIdx.x;
  if (e < NE) atomicAdd(&cnt[ei[NE + e]], 1);
}

// Phase A: per-block local exclusive scan of 256 counters + block sum
__global__ __launch_bounds__(256) void scan_local_kernel(const int* __restrict__ cnt,
                                                         int* __restrict__ row_ptr,
                                                         int* __restrict__ blk_sum) {
  __shared__ int s[256];
  const int b = blockIdx.x, t = threadIdx.x;
  const int i = b * 256 + t;
  int v = (i < NN) ? cnt[i] : 0;
  s[t] = v;
  __syncthreads();
  for (int off = 1; off < 256; off <<= 1) {
    int u = (t >= off) ? s[t - off] : 0;
    __syncthreads();
    s[t] += u;
    __syncthreads();
  }
  if (i < NN) row_ptr[i] = s[t] - v;  // block-local exclusive
  if (t == 255) blk_sum[b] = s[255];
}

// Phase B: scan the 391 block sums (one block)
__global__ __launch_bounds__(512) void scan_blk_kernel(const int* __restrict__ blk_sum,
                                                       int* __restrict__ blk_off) {
  __shared__ int s[512];
  const int t = threadIdx.x;
  int v = (t < NBLK) ? blk_sum[t] : 0;
  s[t] = v;
  __syncthreads();
  for (int off = 1; off < 512; off <<= 1) {
    int u = (t >= off) ? s[t - off] : 0;
    __syncthreads();
    s[t] += u;
    __syncthreads();
  }
  if (t < NBLK) blk_off[t] = s[t] - v;  // exclusive
}

// Phase C: add block offsets, emit row_ptr and next
__global__ __launch_bounds__(256) void scan_add_kernel(int* __restrict__ row_ptr,
                                                       const int* __restrict__ blk_off,
                                                       int* __restrict__ next) {
  const int b = blockIdx.x, t = threadIdx.x;
  const int i = b * 256 + t;
  if (i < NN) {
    int v = row_ptr[i] + blk_off[b];
    row_ptr[i] = v;
    next[i] = v;
  }
  if (i == 0) row_ptr[NN] = NE;
}

__global__ __launch_bounds__(256) void scatter_kernel(const int* __restrict__ ei,
                                                      const float* __restrict__ ew,
                                                      int* __restrict__ next,
                                                      int* __restrict__ col,
                                                      float* __restrict__ wv) {
  int e = blockIdx.x * 256 + threadIdx.x;
  if (e >= NE) return;
  int src = ei[e];
  int dst = ei[NE + e];
  int pos = atomicAdd(&next[dst], 1);
  col[pos] = src;
  wv[pos] = ew[e];
}

// ---------------- GEMM1: h0 = x @ W1, BM=32, thread = 4 rows x 4 cols -------
__global__ __launch_bounds__(256) void gemm1_kernel(const float* __restrict__ x,
                                                    const float* __restrict__ W,
                                                    float* __restrict__ h0) {
  __shared__ float xs[32][DIN];
  const int t = threadIdx.x;
  const int row0 = blockIdx.x * 32;
#pragma unroll
  for (int i = 0; i < 4; ++i) {
    int f = t + i * 256;
    int r = f >> 5, c4 = f & 31;
    *(float4*)&xs[r][c4 * 4] = *(const float4*)&x[(size_t)(row0 + r) * DIN + c4 * 4];
  }
  __syncthreads();
  const int j0 = (t & 31) * 4;
  const int r0 = (t >> 5) * 4;
  float4 acc[4];
#pragma unroll
  for (int i = 0; i < 4; ++i) acc[i] = make_float4(0.f, 0.f, 0.f, 0.f);
  for (int k0 = 0; k0 < DIN; k0 += 4) {
    float4 w[4];
#pragma unroll
    for (int kk = 0; kk < 4; ++kk) w[kk] = *(const float4*)&W[(k0 + kk) * DIN + j0];
#pragma unroll
    for (int i = 0; i < 4; ++i) {
      float4 xr = *(const float4*)&xs[r0 + i][k0];
      acc[i].x += xr.x * w[0].x + xr.y * w[1].x + xr.z * w[2].x + xr.w * w[3].x;
      acc[i].y += xr.x * w[0].y + xr.y * w[1].y + xr.z * w[2].y + xr.w * w[3].y;
      acc[i].z += xr.x * w[0].z + xr.y * w[1].z + xr.z * w[2].z + xr.w * w[3].z;
      acc[i].w += xr.x * w[0].w + xr.y * w[1].w + xr.z * w[2].w + xr.w * w[3].w;
    }
  }
#pragma unroll
  for (int i = 0; i < 4; ++i)
    *(float4*)&h0[(size_t)(row0 + r0 + i) * DIN + j0] = acc[i];
}

// ---------------- GEMM2: h2 = relu(h1 + b1) @ W2, BM=64 ---------------------
__global__ __launch_bounds__(256) void gemm2_kernel(const float* __restrict__ h1,
                                                    const float* __restrict__ b1,
                                                    const float* __restrict__ W2,
                                                    float* __restrict__ h2) {
  __shared__ float xs[64][DIN];
  const int t = threadIdx.x;
  const int row0 = blockIdx.x * 64;
#pragma unroll
  for (int i = 0; i < 8; ++i) {
    int f = t + i * 256;
    int r = f >> 5, c4 = f & 31;
    int gr = row0 + r;
    float4 v;
    if (gr < NN) {
      v = *(const float4*)&h1[(size_t)gr * DIN + c4 * 4];
      float4 b = *(const float4*)&b1[c4 * 4];
      v.x = fmaxf(v.x + b.x, 0.f);
      v.y = fmaxf(v.y + b.y, 0.f);
      v.z = fmaxf(v.z + b.z, 0.f);
      v.w = fmaxf(v.w + b.w, 0.f);
    } else {
      v = make_float4(0.f, 0.f, 0.f, 0.f);
    }
    *(float4*)&xs[r][c4 * 4] = v;
  }
  __syncthreads();
  const int j0 = (t & 15) * 4;
  const int r0 = (t >> 4) * 4;
  float4 acc[4];
#pragma unroll
  for (int i = 0; i < 4; ++i) acc[i] = make_float4(0.f, 0.f, 0.f, 0.f);
  for (int k0 = 0; k0 < DIN; k0 += 4) {
    float4 w[4];
#pragma unroll
    for (int kk = 0; kk < 4; ++kk) w[kk] = *(const float4*)&W2[(k0 + kk) * DOUT + j0];
#pragma unroll
    for (int i = 0; i < 4; ++i) {
      float4 xr = *(const float4*)&xs[r0 + i][k0];
      acc[i].x += xr.x * w[0].x + xr.y * w[1].x + xr.z * w[2].x + xr.w * w[3].x;
      acc[i].y += xr.x * w[0].y + xr.y * w[1].y + xr.z * w[2].y + xr.w * w[3].y;
      acc[i].z += xr.x * w[0].z + xr.y * w[1].z + xr.z * w[2].z + xr.w * w[3].z;
      acc[i].w += xr.x * w[0].w + xr.y * w[1].w + xr.z * w[2].w + xr.w * w[3].w;
    }
  }
#pragma unroll
  for (int i = 0; i < 4; ++i) {
    int gr = row0 + r0 + i;
    if (gr < NN) *(float4*)&h2[(size_t)gr * DOUT + j0] = acc[i];
  }
}

// ---------------- gather SpMM: out[r] = sum_{e in row r} w_e * h[col[e]] ----
template <int D, int LPE, bool BIAS>
__global__ __launch_bounds__(256) void spmm_gather_kernel(const int* __restrict__ rp,
                                                          const int* __restrict__ col,
                                                          const float* __restrict__ wv,
                                                          const float* __restrict__ h,
                                                          const float* __restrict__ bias,
                                                          float* __restrict__ out) {
  const int row = blockIdx.x * (256 / LPE) + threadIdx.x / LPE;
  const int lane = threadIdx.x % LPE;
  if (row >= NN) return;
  const int b = rp[row], e = rp[row + 1];
  float4 acc = make_float4(0.f, 0.f, 0.f, 0.f);
  for (int i = b; i < e; ++i) {
    int s = col[i];
    float w = wv[i];
    float4 v = *(const float4*)&h[(size_t)s * D + lane * 4];
    acc.x += w * v.x;
    acc.y += w * v.y;
    acc.z += w * v.z;
    acc.w += w * v.w;
  }
  if (BIAS) {
    float4 bv = ((const float4*)bias)[lane];
    acc.x += bv.x; acc.y += bv.y; acc.z += bv.z; acc.w += bv.w;
  }
  *(float4*)&out[(size_t)row * D + lane * 4] = acc;
}

extern "C" void kernel_launch(void* const* d_in, const int* in_sizes, int n_in,
                              void* d_out, int out_size, void* d_ws, size_t ws_size,
                              hipStream_t stream) {
  const float* x  = (const float*)d_in[0];
  const int*   ei = (const int*)d_in[1];   // [2, E] row-major int32
  const float* ew = (const float*)d_in[2];
  const float* W1 = (const float*)d_in[3];
  const float* b1 = (const float*)d_in[4];
  const float* W2 = (const float*)d_in[5];
  const float* b2 = (const float*)d_in[6];
  float* out = (float*)d_out;

  // workspace layout
  char* p = (char*)d_ws;
  int*   cnt     = (int*)p;                 p += sizeof(int) * NN;
  int*   row_ptr = (int*)p;                 p += sizeof(int) * (NN + 4);
  int*   next    = (int*)p;                 p += sizeof(int) * NN;
  int*   blk_sum = (int*)p;                 p += sizeof(int) * (NBLK + 1);
  int*   blk_off = (int*)p;                 p += sizeof(int) * (NBLK + 1);
  int*   col     = (int*)p;                 p += sizeof(int) * NE;
  float* wv      = (float*)p;               p += sizeof(float) * NE;
  float* h0      = (float*)p;               p += sizeof(float) * (size_t)NN * DIN;
  float* acc1    = (float*)p;               // [NN, DIN]
  float* h2      = h0;                      // reuse h0 region after spmm1

  // CSR build (shared by both layers)
  hipMemsetAsync(cnt, 0, sizeof(int) * NN, stream);
  hist_kernel<<<(NE + 255) / 256, 256, 0, stream>>>(ei, cnt);
  scan_local_kernel<<<NBLK, 256, 0, stream>>>(cnt, row_ptr, blk_sum);
  scan_blk_kernel<<<1, 512, 0, stream>>>(blk_sum, blk_off);
  scan_add_kernel<<<NBLK, 256, 0, stream>>>(row_ptr, blk_off, next);
  scatter_kernel<<<(NE + 255) / 256, 256, 0, stream>>>(ei, ew, next, col, wv);

  // layer 1
  gemm1_kernel<<<NN / 32, 256, 0, stream>>>(x, W1, h0);
  spmm_gather_kernel<DIN, 32, false>
      <<<(NN * 32 + 255) / 256, 256, 0, stream>>>(row_ptr, col, wv, h0, nullptr, acc1);

  // layer 2
  gemm2_kernel<<<(NN + 63) / 64, 256, 0, stream>>>(acc1, b1, W2, h2);
  spmm_gather_kernel<DOUT, 16, true>
      <<<(NN * 16 + 255) / 256, 256, 0, stream>>>(row_ptr, col, wv, h2, b2, out);
}